// Round 5
// baseline (379.710 us; speedup 1.0000x reference)
//
#include <hip/hip_runtime.h>
#include <hip/hip_bf16.h>

#define BB 8
#define TT 2048
#define DD 512
#define SQRTD 22.62741699796952f

typedef float fv4 __attribute__((ext_vector_type(4)));
typedef short bv8 __attribute__((ext_vector_type(8)));
typedef short bv4 __attribute__((ext_vector_type(4)));

__device__ __forceinline__ short f2bf(float f) {
  __hip_bfloat16 h = __float2bfloat16(f);
  return *reinterpret_cast<short*>(&h);
}
__device__ __forceinline__ float bf2f(short s) {
  union { unsigned u; float f; } a; a.u = ((unsigned)(unsigned short)s) << 16;
  return a.f;
}

__device__ __forceinline__ void gld_lds16(const void* g, void* l) {
  __builtin_amdgcn_global_load_lds(
      (const __attribute__((address_space(1))) void*)g,
      (__attribute__((address_space(3))) void*)l, 16, 0, 0);
}

// ---------------- K1: fused projection GEMM: C = X @ W^T (f32 in, bf16 out)
__global__ __launch_bounds__(256, 2) void k_proj(
    const float* __restrict__ Xq, const float* __restrict__ Xk, const float* __restrict__ Xv,
    const float* __restrict__ Wq, const float* __restrict__ Wk, const float* __restrict__ Wv,
    short* __restrict__ Qb, short* __restrict__ Kb, short* __restrict__ Vb)
{
  __shared__ short At[128 * 64];
  __shared__ short Bt[128 * 64];
  const int z = blockIdx.z;
  const float* __restrict__ X = (z == 0) ? Xq : (z == 1) ? Xk : Xv;
  const float* __restrict__ W = (z == 0) ? Wq : (z == 1) ? Wk : Wv;
  short* __restrict__ C = (z == 0) ? Qb : (z == 1) ? Kb : Vb;
  const int m0 = blockIdx.x * 128;
  const int n0 = blockIdx.y * 128;
  const int t = threadIdx.x;
  const int lane = t & 63;
  const int w = t >> 6;
  const int wr = (w >> 1) * 64, wc = (w & 1) * 64;
  fv4 acc[4][4] = {};
  for (int kt = 0; kt < DD; kt += 64) {
    #pragma unroll
    for (int j = 0; j < 8; ++j) {
      int f = j * 256 + t;
      int row = f >> 4, c4 = f & 15;
      int byte = (row * 128 + c4 * 8) ^ ((row & 7) << 4);
      fv4 va = *(const fv4*)(X + (size_t)(m0 + row) * DD + kt + c4 * 4);
      bv4 ha;
      #pragma unroll
      for (int e = 0; e < 4; ++e) ha[e] = f2bf(va[e]);
      *(bv4*)((char*)At + byte) = ha;
      fv4 vb = *(const fv4*)(W + (size_t)(n0 + row) * DD + kt + c4 * 4);
      bv4 hb;
      #pragma unroll
      for (int e = 0; e < 4; ++e) hb[e] = f2bf(vb[e]);
      *(bv4*)((char*)Bt + byte) = hb;
    }
    __syncthreads();
    #pragma unroll
    for (int ks = 0; ks < 2; ++ks) {
      bv8 af[4], bfr[4];
      #pragma unroll
      for (int i = 0; i < 4; ++i) {
        int ra = wr + i * 16 + (lane & 15);
        af[i] = *(bv8*)((char*)At + ((ra * 128 + ks * 64 + ((lane >> 4) * 16)) ^ ((ra & 7) << 4)));
        int rb = wc + i * 16 + (lane & 15);
        bfr[i] = *(bv8*)((char*)Bt + ((rb * 128 + ks * 64 + ((lane >> 4) * 16)) ^ ((rb & 7) << 4)));
      }
      #pragma unroll
      for (int mi = 0; mi < 4; ++mi)
        #pragma unroll
        for (int ni = 0; ni < 4; ++ni)
          acc[mi][ni] = __builtin_amdgcn_mfma_f32_16x16x32_bf16(af[mi], bfr[ni], acc[mi][ni], 0, 0, 0);
    }
    __syncthreads();
  }
  #pragma unroll
  for (int mi = 0; mi < 4; ++mi)
    #pragma unroll
    for (int r = 0; r < 4; ++r) {
      int gm = m0 + wr + mi * 16 + ((lane >> 4) << 2) + r;
      #pragma unroll
      for (int ni = 0; ni < 4; ++ni) {
        int gn = n0 + wc + ni * 16 + (lane & 15);
        C[(size_t)gm * DD + gn] = f2bf(acc[mi][ni][r]);
      }
    }
}

// ---------------- K1b: transpose V (B,T,D) -> Vt (B,D,T), bf16
__global__ __launch_bounds__(256) void k_transpose(
    const short* __restrict__ Vb, short* __restrict__ Vt)
{
  __shared__ short tile[64][72];
  const int b = blockIdx.z;
  const int t0 = blockIdx.x * 64;
  const int d0 = blockIdx.y * 64;
  const int t = threadIdx.x;
  #pragma unroll
  for (int j = 0; j < 2; ++j) {
    int f = j * 256 + t;
    int row = f >> 3, c8 = f & 7;
    bv8 v = *(const bv8*)(Vb + ((size_t)b * TT + t0 + row) * DD + d0 + c8 * 8);
    *(bv8*)&tile[row][c8 * 8] = v;
  }
  __syncthreads();
  #pragma unroll
  for (int j = 0; j < 2; ++j) {
    int f = j * 256 + t;
    int drow = f >> 3, c8 = f & 7;
    bv8 v;
    #pragma unroll
    for (int e = 0; e < 8; ++e) v[e] = tile[c8 * 8 + e][drow];
    *(bv8*)(Vt + ((size_t)b * DD + d0 + drow) * TT + t0 + c8 * 8) = v;
  }
}

// ---------------- K2: fused attention, KVBLK=64 double-buffered.
// QBLK=64 q-rows, 8 waves (rg=q 16-group 0..3, kg=key 32-half 0..1), 32 strips.
// K(t+1) via global_load_lds into alternate buffer (pre-swizzled source);
// counted vmcnt(8) at top barrier (glds retired, mask prefetch in flight);
// mask prefetched 2 strips ahead (parity register sets); V same-strip from L2.
__global__ __launch_bounds__(512, 2) void k_attn(
    const short* __restrict__ Qb, const short* __restrict__ Kb,
    const short* __restrict__ Vt, const float* __restrict__ mask,
    float* __restrict__ Out)
{
  __shared__ short Ks[2][64 * 512];  // 2 x 64KB, rows of 1KB, linear dest
  __shared__ short Ps[64 * 64];      // 8KB, rows of 128B, XOR-swizzled
  __shared__ float ls[4][2][16];
  const int b = blockIdx.x;          // batch on x => XCD-pinned
  const int q0 = blockIdx.y * 64;
  const int t = threadIdx.x;
  const int lane = t & 63;
  const int w = t >> 6;              // 0..7
  const int rg = w >> 1, kg = w & 1;
  const int l15 = lane & 15, l4 = lane >> 4;
  const int lo16 = lane * 16;

  const char* __restrict__ Kbase = (const char*)(Kb + (size_t)b * TT * DD);
  const float* __restrict__ Mbase = mask + ((size_t)b * TT + q0) * TT;

  // hoist Q fragments: 16 rows (rg group), full D=512
  bv8 qf[16];
  #pragma unroll
  for (int kk = 0; kk < 16; ++kk)
    qf[kk] = *(const bv8*)(Qb + ((size_t)b * TT + q0 + rg * 16 + l15) * DD + kk * 32 + l4 * 8);

  fv4 o[4][4] = {};
  float rsum[4] = {0.f, 0.f, 0.f, 0.f};
  float mk0[8], mk1[8];   // mask sets for even/odd strips: [ct*4 + r]

  // prologue: glds K strip 0 -> buf0 (wave w owns rows [8w,8w+8))
  #pragma unroll
  for (int i = 0; i < 8; ++i) {
    int row = w * 8 + i;
    gld_lds16(Kbase + row * 1024 + (lo16 ^ ((row & 7) << 4)), &Ks[0][row * 512]);
  }
  // prologue: mask(0)->mk0, mask(1)->mk1
  #pragma unroll
  for (int ct = 0; ct < 2; ++ct)
    #pragma unroll
    for (int r = 0; r < 4; ++r) {
      mk0[ct * 4 + r] = Mbase[(size_t)(rg * 16 + l4 * 4 + r) * TT + 0 * 64 + kg * 32 + ct * 16 + l15];
      mk1[ct * 4 + r] = Mbase[(size_t)(rg * 16 + l4 * 4 + r) * TT + 1 * 64 + kg * 32 + ct * 16 + l15];
    }

  for (int p = 0; p < TT / 128; ++p) {
    #pragma unroll
    for (int par = 0; par < 2; ++par) {
      const int s = p * 2 + par;
      const int sn = (s + 1) & (TT / 64 - 1);
      const short* KsR = Ks[par];
      short* KsW = (short*)Ks[par ^ 1];
      float* mko = par ? mk1 : mk0;

      // bar-top: K(s) glds retired (vmcnt(8) leaves the 8 mask loads in flight)
      asm volatile("s_waitcnt vmcnt(8) lgkmcnt(0)\n\ts_barrier" ::: "memory");
      __builtin_amdgcn_sched_barrier(0);

      // V(s): wave owns d-cols [64w, 64w+64), k = 64 keys
      bv8 vreg[4][2];
      #pragma unroll
      for (int ni = 0; ni < 4; ++ni)
        #pragma unroll
        for (int ks = 0; ks < 2; ++ks)
          vreg[ni][ks] = *(const bv8*)(Vt + ((size_t)b * DD + w * 64 + ni * 16 + l15) * TT + s * 64 + ks * 32 + l4 * 8);

      // issue glds K(s+1) -> other buffer
      const char* Kstrip = Kbase + (size_t)sn * 64 * 1024;
      #pragma unroll
      for (int i = 0; i < 8; ++i) {
        int row = w * 8 + i;
        gld_lds16(Kstrip + row * 1024 + (lo16 ^ ((row & 7) << 4)), KsW + row * 512);
      }
      __builtin_amdgcn_sched_barrier(0);

      // QK^T: two 16x16 tiles (ct), K=512, 2 chains per tile
      fv4 sA0 = {}, sA1 = {}, sB0 = {}, sB1 = {};
      const int krow0 = kg * 32 + l15;
      const int krow1 = kg * 32 + 16 + l15;
      const int sw0 = (krow0 & 7) << 4, sw1 = (krow1 & 7) << 4;
      __builtin_amdgcn_s_setprio(1);
      #pragma unroll
      for (int kk = 0; kk < 16; kk += 2) {
        bv8 a0 = *(const bv8*)((const char*)KsR + krow0 * 1024 + (((kk + 0) * 64 + l4 * 16) ^ sw0));
        bv8 a1 = *(const bv8*)((const char*)KsR + krow0 * 1024 + (((kk + 1) * 64 + l4 * 16) ^ sw0));
        bv8 b0 = *(const bv8*)((const char*)KsR + krow1 * 1024 + (((kk + 0) * 64 + l4 * 16) ^ sw1));
        bv8 b1 = *(const bv8*)((const char*)KsR + krow1 * 1024 + (((kk + 1) * 64 + l4 * 16) ^ sw1));
        sA0 = __builtin_amdgcn_mfma_f32_16x16x32_bf16(qf[kk + 0], a0, sA0, 0, 0, 0);
        sB0 = __builtin_amdgcn_mfma_f32_16x16x32_bf16(qf[kk + 0], b0, sB0, 0, 0, 0);
        sA1 = __builtin_amdgcn_mfma_f32_16x16x32_bf16(qf[kk + 1], a1, sA1, 0, 0, 0);
        sB1 = __builtin_amdgcn_mfma_f32_16x16x32_bf16(qf[kk + 1], b1, sB1, 0, 0, 0);
      }
      __builtin_amdgcn_s_setprio(0);
      fv4 sa0 = sA0 + sA1;
      fv4 sa1 = sB0 + sB1;

      // epilogue: scale + mask + exp -> Ps (swizzled), partial row sums
      #pragma unroll
      for (int ct = 0; ct < 2; ++ct) {
        fv4 sv = ct ? sa1 : sa0;
        #pragma unroll
        for (int r = 0; r < 4; ++r) {
          int row = rg * 16 + l4 * 4 + r;
          float sx = sv[r] * SQRTD + mko[ct * 4 + r];
          float pv = __expf(sx);
          short pb = f2bf(pv);
          rsum[r] += bf2f(pb);
          int col = kg * 32 + ct * 16 + l15;
          *((short*)((char*)Ps + ((row * 128 + col * 2) ^ ((row & 7) << 4)))) = pb;
        }
      }
      // issue mask(s+2) into the set just consumed (lands before epi(s+2))
      {
        const int s2 = (s + 2) & (TT / 64 - 1);
        #pragma unroll
        for (int ct = 0; ct < 2; ++ct)
          #pragma unroll
          for (int r = 0; r < 4; ++r)
            mko[ct * 4 + r] = Mbase[(size_t)(rg * 16 + l4 * 4 + r) * TT + (size_t)s2 * 64 + kg * 32 + ct * 16 + l15];
      }

      // bar-mid: Ps visible; all waves done reading KsR. No vmcnt drain.
      asm volatile("s_waitcnt lgkmcnt(0)\n\ts_barrier" ::: "memory");
      __builtin_amdgcn_sched_barrier(0);

      // PV: O[64q x 64d] per wave, k = 64 keys
      __builtin_amdgcn_s_setprio(1);
      #pragma unroll
      for (int mi = 0; mi < 4; ++mi) {
        int prow = mi * 16 + l15;
        int psw = (prow & 7) << 4;
        bv8 pa0 = *(const bv8*)((const char*)Ps + prow * 128 + ((0 * 64 + l4 * 16) ^ psw));
        bv8 pa1 = *(const bv8*)((const char*)Ps + prow * 128 + ((1 * 64 + l4 * 16) ^ psw));
        #pragma unroll
        for (int ni = 0; ni < 4; ++ni) {
          o[mi][ni] = __builtin_amdgcn_mfma_f32_16x16x32_bf16(pa0, vreg[ni][0], o[mi][ni], 0, 0, 0);
          o[mi][ni] = __builtin_amdgcn_mfma_f32_16x16x32_bf16(pa1, vreg[ni][1], o[mi][ni], 0, 0, 0);
        }
      }
      __builtin_amdgcn_s_setprio(0);
    }
  }

  // row-sum reduction over 16 key-residues, then across kg
  #pragma unroll
  for (int r = 0; r < 4; ++r) {
    float v = rsum[r];
    v += __shfl_xor(v, 1);
    v += __shfl_xor(v, 2);
    v += __shfl_xor(v, 4);
    v += __shfl_xor(v, 8);
    if (l15 == 0) ls[rg][kg][l4 * 4 + r] = v;
  }
  __syncthreads();
  #pragma unroll
  for (int mi = 0; mi < 4; ++mi)
    #pragma unroll
    for (int r = 0; r < 4; ++r) {
      int idx = l4 * 4 + r;
      float inv = 1.0f / (ls[mi][0][idx] + ls[mi][1][idx]);
      int grow = q0 + mi * 16 + idx;
      #pragma unroll
      for (int ni = 0; ni < 4; ++ni)
        Out[((size_t)b * TT + grow) * DD + w * 64 + ni * 16 + l15] = o[mi][ni][r] * inv;
    }
}

extern "C" void kernel_launch(void* const* d_in, const int* in_sizes, int n_in,
                              void* d_out, int out_size, void* d_ws, size_t ws_size,
                              hipStream_t stream) {
  const float* ft_q = (const float*)d_in[0];
  const float* ft_k = (const float*)d_in[1];
  const float* ft_v = (const float*)d_in[2];
  const float* mask = (const float*)d_in[3];
  const float* Wq   = (const float*)d_in[4];
  const float* Wk   = (const float*)d_in[5];
  const float* Wv   = (const float*)d_in[6];
  float* Out = (float*)d_out;

  const size_t nBTD = (size_t)BB * TT * DD;
  short* Qb = (short*)d_ws;
  short* Kb = Qb + nBTD;
  short* Vb = Kb + nBTD;
  short* Vt = Vb + nBTD;

  k_proj<<<dim3(128, 4, 3), 256, 0, stream>>>(ft_q, ft_k, ft_v, Wq, Wk, Wv, Qb, Kb, Vb);
  k_transpose<<<dim3(TT / 64, DD / 64, BB), 256, 0, stream>>>(Vb, Vt);
  k_attn<<<dim3(BB, TT / 64), 512, 0, stream>>>(Qb, Kb, Vt, mask, Out);
}